// Round 2
// baseline (351.984 us; speedup 1.0000x reference)
//
#include <hip/hip_runtime.h>
#include <stdint.h>

#define BATCH 2
#define SEQ 2048
#define DMODEL 1024
#define NHEAD 16
#define HDIM 64

typedef __attribute__((ext_vector_type(8))) short bf16x8;
typedef __attribute__((ext_vector_type(4))) float f32x4;

__device__ __forceinline__ unsigned short f2bf(float f) {
  unsigned int u = __float_as_uint(f);
  u += 0x7fffu + ((u >> 16) & 1u);
  return (unsigned short)(u >> 16);
}
__device__ __forceinline__ void async_copy16(const void* g, void* l) {
  __builtin_amdgcn_global_load_lds(
      (const __attribute__((address_space(1))) void*)g,
      (__attribute__((address_space(3))) void*)l, 16, 0, 0);
}

// ---- fp32 -> bf16 elementwise conversion (n4 = n/4 float4 groups) ----
__global__ __launch_bounds__(256) void cvt_kernel(
    const float* __restrict__ src, unsigned short* __restrict__ dst, int n4) {
  const int idx = blockIdx.x * 256 + threadIdx.x;
  if (idx < n4) {
    const float4 v = ((const float4*)src)[idx];
    ushort4 o;
    o.x = f2bf(v.x); o.y = f2bf(v.y); o.z = f2bf(v.z); o.w = f2bf(v.w);
    ((ushort4*)dst)[idx] = o;
  }
}

// ---- mask lengths: klen[b] at lens[0..1], qlen[b] at lens[2..3] ----
// Detect storage: byte-format iff base[1]!=0 (element 1 always valid since
// len >= S/2; int32 little-endian word value 1 has byte1 == 0).
__global__ __launch_bounds__(256) void lens_kernel(
    const unsigned char* __restrict__ kp, const unsigned char* __restrict__ qp,
    int* __restrict__ lens) {
  const int t = threadIdx.x;
  const int wave = t >> 6, lane = t & 63;
  const unsigned char* base = (wave < 2) ? kp : qp;
  const int b = wave & 1;
  const bool bytefmt = (base[1] != 0);
  int cnt = 0;
  for (int p = lane; p < SEQ; p += 64) {
    int nz;
    if (bytefmt) nz = (base[(size_t)b * SEQ + p] != 0) ? 1 : 0;
    else nz = (((const int*)base)[(size_t)b * SEQ + p] != 0) ? 1 : 0;
    cnt += nz;
  }
#pragma unroll
  for (int off = 32; off >= 1; off >>= 1) cnt += __shfl_xor(cnt, off, 64);
  if (lane == 0) lens[wave] = cnt;
}

// ---- fused QKV projection: dst[b,h,s,hd] = x @ W^T + bias (bf16 in, bf16 out)
// 128x128 tile, BK=32, 4 waves each 64x64 (4x4 16x16x32 mfma frags).
__global__ __launch_bounds__(256) void qkv_proj(
    const unsigned short* __restrict__ xq, const unsigned short* __restrict__ xk,
    const unsigned short* __restrict__ xv,
    const unsigned short* __restrict__ Wq, const float* __restrict__ bq,
    const unsigned short* __restrict__ Wk, const float* __restrict__ bk,
    const unsigned short* __restrict__ Wv, const float* __restrict__ bv,
    unsigned short* __restrict__ Qo, unsigned short* __restrict__ Ko,
    unsigned short* __restrict__ Vo) {
  const int z = blockIdx.z;
  const unsigned short* x = (z == 0) ? xq : (z == 1) ? xk : xv;
  const unsigned short* W = (z == 0) ? Wq : (z == 1) ? Wk : Wv;
  const float* bias = (z == 0) ? bq : (z == 1) ? bk : bv;
  unsigned short* dst = (z == 0) ? Qo : (z == 1) ? Ko : Vo;

  __shared__ unsigned short As[128 * 32];
  __shared__ unsigned short Bs[128 * 32];

  const int t = threadIdx.x;
  const int wave = t >> 6, lane = t & 63, quad = lane >> 4, l16 = lane & 15;
  const int wm = wave >> 1, wn = wave & 1;
  const int m0 = blockIdx.y * 128;
  const int n0 = blockIdx.x * 128;

  const f32x4 fz = {0.f, 0.f, 0.f, 0.f};
  f32x4 acc[4][4];
#pragma unroll
  for (int i = 0; i < 4; i++)
#pragma unroll
    for (int j = 0; j < 4; j++) acc[i][j] = fz;

  for (int k0 = 0; k0 < DMODEL; k0 += 32) {
    __syncthreads();
#pragma unroll
    for (int c = 0; c < 2; c++) {
      const int g = c * 256 + t;
      const int row = g >> 2, cc = g & 3;
      async_copy16(x + (size_t)(m0 + row) * DMODEL + k0 + cc * 8,
                   (char*)As + (c * 256 + wave * 64) * 16);
      async_copy16(W + (size_t)(n0 + row) * DMODEL + k0 + cc * 8,
                   (char*)Bs + (c * 256 + wave * 64) * 16);
    }
    __syncthreads();
    bf16x8 af[4], bfr[4];
#pragma unroll
    for (int i = 0; i < 4; i++) {
      af[i] = *(const bf16x8*)(As + (wm * 64 + i * 16 + l16) * 32 + quad * 8);
      bfr[i] = *(const bf16x8*)(Bs + (wn * 64 + i * 16 + l16) * 32 + quad * 8);
    }
#pragma unroll
    for (int i = 0; i < 4; i++)
#pragma unroll
      for (int j = 0; j < 4; j++)
        acc[i][j] = __builtin_amdgcn_mfma_f32_16x16x32_bf16(af[i], bfr[j], acc[i][j], 0, 0, 0);
  }

#pragma unroll
  for (int j = 0; j < 4; j++) {
    const int n = n0 + wn * 64 + j * 16 + l16;
    const float bf_ = bias[n];
    const int h = n >> 6, hd = n & 63;
#pragma unroll
    for (int i = 0; i < 4; i++) {
#pragma unroll
      for (int r = 0; r < 4; r++) {
        const int m = m0 + wm * 64 + i * 16 + quad * 4 + r;
        const int bb = m >> 11, s = m & (SEQ - 1);
        dst[(((size_t)(bb * NHEAD + h) * SEQ + s) << 6) + hd] = f2bf(acc[i][j][r] + bf_);
      }
    }
  }
}

// ---- flash attention: block = (qtile 64 rows, h, b); 4 waves x 16 rows ----
__global__ __launch_bounds__(256) void attn_kernel(
    const unsigned short* __restrict__ Qb, const unsigned short* __restrict__ Kb,
    const unsigned short* __restrict__ Vb, const float* __restrict__ qin,
    const int* __restrict__ lens, float* __restrict__ out) {
  const int h = blockIdx.y, b = blockIdx.z;
  const int qb = blockIdx.x * 64;
  const int bh = b * NHEAD + h;
  const int t = threadIdx.x, wave = t >> 6, lane = t & 63, quad = lane >> 4, l16 = lane & 15;
  const int klen = lens[b], qlen = lens[2 + b];

  __shared__ unsigned short Ks[64 * 64];      // [key][d] row-major
  __shared__ unsigned short VT[64 * 72];      // [d][key], stride 72 (16B-aligned rows)
  __shared__ unsigned short Ps[4 * 16 * 72];  // per-wave P tile [16][64], stride 72

  const unsigned short* Qp = Qb + (size_t)bh * SEQ * HDIM;
  const unsigned short* Kp = Kb + (size_t)bh * SEQ * HDIM;
  const unsigned short* Vp = Vb + (size_t)bh * SEQ * HDIM;

  const int qrow = qb + wave * 16 + l16;
  const bf16x8 qf0 = *(const bf16x8*)(Qp + (size_t)qrow * HDIM + quad * 8);
  const bf16x8 qf1 = *(const bf16x8*)(Qp + (size_t)qrow * HDIM + 32 + quad * 8);

  const f32x4 fz = {0.f, 0.f, 0.f, 0.f};
  f32x4 o[4];
#pragma unroll
  for (int i = 0; i < 4; i++) o[i] = fz;
  float mrow[4], lrow[4];
#pragma unroll
  for (int r = 0; r < 4; r++) { mrow[r] = -__builtin_inff(); lrow[r] = 0.f; }

  const float SL2E = 0.18033688011112042f;  // (1/sqrt(64)) * log2(e)
  const int nk_ = (qb + 64 < klen) ? (qb + 64) : klen;
  const int ntiles = (nk_ + 63) >> 6;
  unsigned short* Pw = Ps + wave * 16 * 72;

  for (int kt = 0; kt < ntiles; kt++) {
    const int key0 = kt * 64;
    __syncthreads();
#pragma unroll
    for (int c = 0; c < 2; c++) {
      const int g = c * 256 + t;
      const int key = g >> 3, d8 = (g & 7) * 8;
      async_copy16(Kp + (size_t)(key0 + key) * HDIM + d8,
                   (char*)Ks + (c * 256 + wave * 64) * 16);
    }
#pragma unroll
    for (int c = 0; c < 2; c++) {
      const int g = c * 256 + t;
      const int key = g >> 3, d8 = (g & 7) * 8;
      const bf16x8 vv = *(const bf16x8*)(Vp + (size_t)(key0 + key) * HDIM + d8);
      const int tj = t & 7;
#pragma unroll
      for (int jj = 0; jj < 8; jj++) {       // staggered to spread banks
        const int j = (jj + tj) & 7;
        VT[(d8 + j) * 72 + key] = ((const unsigned short*)&vv)[j];
      }
    }
    __syncthreads();

    f32x4 sc[4];
#pragma unroll
    for (int nf = 0; nf < 4; nf++) {
      const bf16x8 kf0 = *(const bf16x8*)(Ks + (nf * 16 + l16) * 64 + quad * 8);
      const bf16x8 kf1 = *(const bf16x8*)(Ks + (nf * 16 + l16) * 64 + 32 + quad * 8);
      f32x4 a = fz;
      a = __builtin_amdgcn_mfma_f32_16x16x32_bf16(qf0, kf0, a, 0, 0, 0);
      a = __builtin_amdgcn_mfma_f32_16x16x32_bf16(qf1, kf1, a, 0, 0, 0);
      sc[nf] = a;
    }

    float pm[4][4];
#pragma unroll
    for (int nf = 0; nf < 4; nf++) {
      const int j = key0 + nf * 16 + l16;
#pragma unroll
      for (int r = 0; r < 4; r++) {
        const int i = qb + wave * 16 + quad * 4 + r;
        const float vvv = sc[nf][r] * SL2E;
        pm[nf][r] = (j <= i && j < klen) ? vvv : -__builtin_inff();
      }
    }
#pragma unroll
    for (int r = 0; r < 4; r++) {
      float rm = fmaxf(fmaxf(pm[0][r], pm[1][r]), fmaxf(pm[2][r], pm[3][r]));
      rm = fmaxf(rm, __shfl_xor(rm, 1, 64));
      rm = fmaxf(rm, __shfl_xor(rm, 2, 64));
      rm = fmaxf(rm, __shfl_xor(rm, 4, 64));
      rm = fmaxf(rm, __shfl_xor(rm, 8, 64));
      const float mnew = fmaxf(mrow[r], rm);
      const float msub = fmaxf(mnew, -1e30f);  // NaN guard
      const float alpha = exp2f(mrow[r] - msub);
      float rs = 0.f;
#pragma unroll
      for (int nf = 0; nf < 4; nf++) {
        const float p = exp2f(pm[nf][r] - msub);
        pm[nf][r] = p;
        rs += p;
      }
      rs += __shfl_xor(rs, 1, 64);
      rs += __shfl_xor(rs, 2, 64);
      rs += __shfl_xor(rs, 4, 64);
      rs += __shfl_xor(rs, 8, 64);
      lrow[r] = lrow[r] * alpha + rs;
      mrow[r] = mnew;
#pragma unroll
      for (int db = 0; db < 4; db++) o[db][r] *= alpha;
    }

    // P: C-layout -> LDS -> A-layout (wave-private region, no barrier needed)
#pragma unroll
    for (int nf = 0; nf < 4; nf++)
#pragma unroll
      for (int r = 0; r < 4; r++)
        Pw[(quad * 4 + r) * 72 + nf * 16 + l16] = f2bf(pm[nf][r]);

    const bf16x8 pf0 = *(const bf16x8*)(Pw + l16 * 72 + quad * 8);
    const bf16x8 pf1 = *(const bf16x8*)(Pw + l16 * 72 + 32 + quad * 8);
#pragma unroll
    for (int db = 0; db < 4; db++) {
      const bf16x8 vt0 = *(const bf16x8*)(VT + (db * 16 + l16) * 72 + quad * 8);
      const bf16x8 vt1 = *(const bf16x8*)(VT + (db * 16 + l16) * 72 + 32 + quad * 8);
      o[db] = __builtin_amdgcn_mfma_f32_16x16x32_bf16(pf0, vt0, o[db], 0, 0, 0);
      o[db] = __builtin_amdgcn_mfma_f32_16x16x32_bf16(pf1, vt1, o[db], 0, 0, 0);
    }
  }

  float inv[4];
#pragma unroll
  for (int r = 0; r < 4; r++) inv[r] = (lrow[r] > 0.f) ? 1.f / lrow[r] : 0.f;
#pragma unroll
  for (int db = 0; db < 4; db++) {
    const int col = h * HDIM + db * 16 + l16;
#pragma unroll
    for (int r = 0; r < 4; r++) {
      const int i = qb + wave * 16 + quad * 4 + r;
      const size_t oidx = (size_t)(b * SEQ + i) * DMODEL + col;
      const float res = (i < qlen) ? o[db][r] * inv[r] : 0.f;
      out[oidx] = res + qin[oidx];
    }
  }
}

extern "C" void kernel_launch(void* const* d_in, const int* in_sizes, int n_in,
                              void* d_out, int out_size, void* d_ws, size_t ws_size,
                              hipStream_t stream) {
  (void)in_sizes; (void)n_in; (void)out_size; (void)ws_size;
  const float* q = (const float*)d_in[0];
  const float* k = (const float*)d_in[1];
  const float* v = (const float*)d_in[2];
  const float* Wq = (const float*)d_in[3];
  const float* bq = (const float*)d_in[4];
  const float* Wk = (const float*)d_in[5];
  const float* bk = (const float*)d_in[6];
  const float* Wv = (const float*)d_in[7];
  const float* bv = (const float*)d_in[8];
  const unsigned char* kpm = (const unsigned char*)d_in[9];
  const unsigned char* qpm = (const unsigned char*)d_in[10];
  float* out = (float*)d_out;

  const size_t tsz = (size_t)BATCH * SEQ * DMODEL;  // 4 Mi elements
  const size_t wsz = (size_t)DMODEL * DMODEL;       // 1 Mi elements

  char* ws = (char*)d_ws;
  int* lens = (int*)ws;
  unsigned short* qb16 = (unsigned short*)(ws + 256);
  unsigned short* kb16 = qb16 + tsz;
  unsigned short* vb16 = kb16 + tsz;
  unsigned short* Wqb = vb16 + tsz;
  unsigned short* Wkb = Wqb + wsz;
  unsigned short* Wvb = Wkb + wsz;
  unsigned short* Qw = Wvb + wsz;
  unsigned short* Kw = Qw + tsz;
  unsigned short* Vw = Kw + tsz;

  lens_kernel<<<dim3(1), dim3(256), 0, stream>>>(kpm, qpm, lens);
  cvt_kernel<<<dim3((int)(tsz / 4 / 256)), dim3(256), 0, stream>>>(q, qb16, (int)(tsz / 4));
  cvt_kernel<<<dim3((int)(tsz / 4 / 256)), dim3(256), 0, stream>>>(k, kb16, (int)(tsz / 4));
  cvt_kernel<<<dim3((int)(tsz / 4 / 256)), dim3(256), 0, stream>>>(v, vb16, (int)(tsz / 4));
  cvt_kernel<<<dim3((int)(wsz / 4 / 256)), dim3(256), 0, stream>>>(Wq, Wqb, (int)(wsz / 4));
  cvt_kernel<<<dim3((int)(wsz / 4 / 256)), dim3(256), 0, stream>>>(Wk, Wkb, (int)(wsz / 4));
  cvt_kernel<<<dim3((int)(wsz / 4 / 256)), dim3(256), 0, stream>>>(Wv, Wvb, (int)(wsz / 4));
  qkv_proj<<<dim3(8, 32, 3), dim3(256), 0, stream>>>(qb16, kb16, vb16, Wqb, bq, Wkb, bk, Wvb, bv, Qw, Kw, Vw);
  attn_kernel<<<dim3(32, NHEAD, BATCH), dim3(256), 0, stream>>>(Qw, Kw, Vw, q, lens, out);
}

// Round 3
// 262.417 us; speedup vs baseline: 1.3413x; 1.3413x over previous
//
#include <hip/hip_runtime.h>
#include <stdint.h>

#define BATCH 2
#define SEQ 2048
#define DMODEL 1024
#define NHEAD 16
#define HDIM 64

typedef __attribute__((ext_vector_type(8))) short bf16x8;
typedef __attribute__((ext_vector_type(4))) float f32x4;

__device__ __forceinline__ unsigned short f2bf(float f) {
  unsigned int u = __float_as_uint(f);
  u += 0x7fffu + ((u >> 16) & 1u);
  return (unsigned short)(u >> 16);
}
__device__ __forceinline__ void async_copy16(const void* g, void* l) {
  __builtin_amdgcn_global_load_lds(
      (const __attribute__((address_space(1))) void*)g,
      (__attribute__((address_space(3))) void*)l, 16, 0, 0);
}

// ---- fp32 -> bf16 for q,k,v (4Mi el each) + Wq,Wk,Wv (1Mi el each) ----
__global__ __launch_bounds__(256) void cvt_all(
    const float* __restrict__ q, const float* __restrict__ k,
    const float* __restrict__ v, const float* __restrict__ Wq,
    const float* __restrict__ Wk, const float* __restrict__ Wv,
    unsigned short* __restrict__ dst) {
  const int g = blockIdx.x * 256 + threadIdx.x;
  const float* src;
  size_t off, dbase;
  if (g < 3 * (1 << 20)) {
    const int ti = g >> 20;
    src = (ti == 0) ? q : (ti == 1) ? k : v;
    off = (size_t)(g & ((1 << 20) - 1));
    dbase = (size_t)ti << 22;
  } else {
    const int gw = g - 3 * (1 << 20);
    const int ti = gw >> 18;
    src = (ti == 0) ? Wq : (ti == 1) ? Wk : Wv;
    off = (size_t)(gw & ((1 << 18) - 1));
    dbase = (3ull << 22) + ((size_t)ti << 20);
  }
  const float4 x = ((const float4*)src)[off];
  ushort4 o;
  o.x = f2bf(x.x); o.y = f2bf(x.y); o.z = f2bf(x.z); o.w = f2bf(x.w);
  *(ushort4*)(dst + dbase + off * 4) = o;
}

// ---- mask lengths: klen[b] -> lens[0..1], qlen[b] -> lens[2..3] ----
__global__ __launch_bounds__(256) void lens_kernel(
    const unsigned char* __restrict__ kp, const unsigned char* __restrict__ qp,
    int* __restrict__ lens) {
  const int t = threadIdx.x, wave = t >> 6, lane = t & 63;
  const unsigned char* base = (wave < 2) ? kp : qp;
  const int b = wave & 1;
  const bool bytefmt = (base[1] != 0);  // element 1 always valid (len>=S/2)
  int cnt = 0;
  if (bytefmt) {
    const uint4* p = (const uint4*)(base + (size_t)b * SEQ);
#pragma unroll
    for (int g = 0; g < 2; g++) {
      const uint4 x = p[g * 64 + lane];
      const unsigned int w[4] = {x.x, x.y, x.z, x.w};
#pragma unroll
      for (int i = 0; i < 4; i++) {
        const unsigned int ww = w[i];
        cnt += ((ww & 0xffu) != 0) + ((ww & 0xff00u) != 0) +
               ((ww & 0xff0000u) != 0) + ((ww & 0xff000000u) != 0);
      }
    }
  } else {
    const uint4* p = (const uint4*)(base + (size_t)b * SEQ * 4);
#pragma unroll
    for (int g = 0; g < 8; g++) {
      const uint4 x = p[g * 64 + lane];
      cnt += (x.x != 0) + (x.y != 0) + (x.z != 0) + (x.w != 0);
    }
  }
#pragma unroll
  for (int off = 32; off >= 1; off >>= 1) cnt += __shfl_xor(cnt, off, 64);
  if (lane == 0) lens[wave] = cnt;
}

// ---- fused QKV projection (unchanged from R2; LDS reads are 2-way/free) ----
__global__ __launch_bounds__(256) void qkv_proj(
    const unsigned short* __restrict__ xq, const unsigned short* __restrict__ xk,
    const unsigned short* __restrict__ xv,
    const unsigned short* __restrict__ Wq, const float* __restrict__ bq,
    const unsigned short* __restrict__ Wk, const float* __restrict__ bk,
    const unsigned short* __restrict__ Wv, const float* __restrict__ bv,
    unsigned short* __restrict__ Qo, unsigned short* __restrict__ Ko,
    unsigned short* __restrict__ Vo) {
  const int z = blockIdx.z;
  const unsigned short* x = (z == 0) ? xq : (z == 1) ? xk : xv;
  const unsigned short* W = (z == 0) ? Wq : (z == 1) ? Wk : Wv;
  const float* bias = (z == 0) ? bq : (z == 1) ? bk : bv;
  unsigned short* dst = (z == 0) ? Qo : (z == 1) ? Ko : Vo;

  __shared__ unsigned short As[128 * 32];
  __shared__ unsigned short Bs[128 * 32];

  const int t = threadIdx.x;
  const int wave = t >> 6, lane = t & 63, quad = lane >> 4, l16 = lane & 15;
  const int wm = wave >> 1, wn = wave & 1;
  const int m0 = blockIdx.y * 128, n0 = blockIdx.x * 128;

  const f32x4 fz = {0.f, 0.f, 0.f, 0.f};
  f32x4 acc[4][4];
#pragma unroll
  for (int i = 0; i < 4; i++)
#pragma unroll
    for (int j = 0; j < 4; j++) acc[i][j] = fz;

  for (int k0 = 0; k0 < DMODEL; k0 += 32) {
    __syncthreads();
#pragma unroll
    for (int c = 0; c < 2; c++) {
      const int g = c * 256 + t;
      const int row = g >> 2, cc = g & 3;
      async_copy16(x + (size_t)(m0 + row) * DMODEL + k0 + cc * 8,
                   (char*)As + (c * 256 + (t & 192)) * 16);
      async_copy16(W + (size_t)(n0 + row) * DMODEL + k0 + cc * 8,
                   (char*)Bs + (c * 256 + (t & 192)) * 16);
    }
    __syncthreads();
    bf16x8 af[4], bfr[4];
#pragma unroll
    for (int i = 0; i < 4; i++) {
      af[i] = *(const bf16x8*)(As + (wm * 64 + i * 16 + l16) * 32 + quad * 8);
      bfr[i] = *(const bf16x8*)(Bs + (wn * 64 + i * 16 + l16) * 32 + quad * 8);
    }
#pragma unroll
    for (int i = 0; i < 4; i++)
#pragma unroll
      for (int j = 0; j < 4; j++)
        acc[i][j] = __builtin_amdgcn_mfma_f32_16x16x32_bf16(af[i], bfr[j], acc[i][j], 0, 0, 0);
  }

#pragma unroll
  for (int j = 0; j < 4; j++) {
    const int n = n0 + wn * 64 + j * 16 + l16;
    const float bf_ = bias[n];
    const int h = n >> 6, hd = n & 63;
#pragma unroll
    for (int i = 0; i < 4; i++) {
#pragma unroll
      for (int r = 0; r < 4; r++) {
        const int m = m0 + wm * 64 + i * 16 + quad * 4 + r;
        const int bb = m >> 11, s = m & (SEQ - 1);
        dst[(((size_t)(bb * NHEAD + h) * SEQ + s) << 6) + hd] = f2bf(acc[i][j][r] + bf_);
      }
    }
  }
}

// ======================= attention v2 =======================
// Pairing: block pi handles q-tiles lo=pi, hi=31-pi jointly (uniform 33
// MFMA-tiles). Swapped QK mfma(kf,qf) -> P^T[key][q]: per-lane softmax.
// All LDS arrays XOR-swizzled: phys 16B-group = logical ^ (row&7).

__device__ __forceinline__ void stage_K(const unsigned short* __restrict__ Kp,
                                        int key0, unsigned short* dst, int t) {
#pragma unroll
  for (int c = 0; c < 2; c++) {
    const int slot = c * 256 + t;
    const int row = slot >> 3, pg = slot & 7;
    const int lg = pg ^ (row & 7);
    async_copy16(Kp + (size_t)(key0 + row) * HDIM + lg * 8,
                 (char*)dst + (c * 256 + (t & 192)) * 16);
  }
}

__device__ __forceinline__ void load_V(const unsigned short* __restrict__ Vp,
                                       int key0, int t, bf16x8& a, bf16x8& b) {
  a = *(const bf16x8*)(Vp + (size_t)(key0 + (t >> 3)) * HDIM + (t & 7) * 8);
  const int s1 = 256 + t;
  b = *(const bf16x8*)(Vp + (size_t)(key0 + (s1 >> 3)) * HDIM + (s1 & 7) * 8);
}

__device__ __forceinline__ void write_VT(unsigned short* vt, int t, bf16x8 a, bf16x8 b) {
#pragma unroll
  for (int c = 0; c < 2; c++) {
    const int slot = c * 256 + t;
    const int key = slot >> 3, u = slot & 7;
    const int K8 = key >> 3, k7 = key & 7;
    const bf16x8 vv = c ? b : a;
#pragma unroll
    for (int jj = 0; jj < 8; jj++) {  // staggered: 2-way banks
      const int j = (jj + u) & 7;
      vt[(u * 8 + j) * 64 + ((K8 ^ j) * 8) + k7] = ((const unsigned short*)&vv)[j];
    }
  }
}

__device__ __forceinline__ void softmax_update(
    const f32x4 s[4], int key0, int qrow, int klen, int quad, int l16,
    float& m, float& l, f32x4 o[4], unsigned short* Pdst) {
  const float SL2E = 0.18033688011112042f;  // (1/sqrt(64)) * log2(e)
  const int sw = l16 & 7;
  float pm[4][4];
  float rm = -__builtin_inff();
#pragma unroll
  for (int nf = 0; nf < 4; nf++)
#pragma unroll
    for (int r = 0; r < 4; r++) {
      const int key = key0 + nf * 16 + quad * 4 + r;
      const float vv = s[nf][r] * SL2E;
      pm[nf][r] = (key <= qrow && key < klen) ? vv : -__builtin_inff();
      rm = fmaxf(rm, pm[nf][r]);
    }
  rm = fmaxf(rm, __shfl_xor(rm, 16, 64));
  rm = fmaxf(rm, __shfl_xor(rm, 32, 64));
  const float mnew = fmaxf(m, rm);
  const float msub = fmaxf(mnew, -1e30f);  // NaN guard
  const float alpha = exp2f(m - msub);
  float rs = 0.f;
#pragma unroll
  for (int nf = 0; nf < 4; nf++)
#pragma unroll
    for (int r = 0; r < 4; r++) {
      const float p = exp2f(pm[nf][r] - msub);
      pm[nf][r] = p;
      rs += p;
    }
  rs += __shfl_xor(rs, 16, 64);
  rs += __shfl_xor(rs, 32, 64);
  l = l * alpha + rs;
  m = mnew;
  float ab[4];
#pragma unroll
  for (int r = 0; r < 4; r++) ab[r] = __shfl(alpha, quad * 4 + r, 64);
#pragma unroll
  for (int db = 0; db < 4; db++)
#pragma unroll
    for (int r = 0; r < 4; r++) o[db][r] *= ab[r];
#pragma unroll
  for (int nf = 0; nf < 4; nf++) {
    ushort4 pk;
    pk.x = f2bf(pm[nf][0]); pk.y = f2bf(pm[nf][1]);
    pk.z = f2bf(pm[nf][2]); pk.w = f2bf(pm[nf][3]);
    const int grp = (nf * 2 + (quad >> 1)) ^ sw;
    *(ushort4*)(Pdst + l16 * 64 + grp * 8 + (quad & 1) * 4) = pk;
  }
}

__global__ __launch_bounds__(256, 2) void attn_kernel(
    const unsigned short* __restrict__ Qb, const unsigned short* __restrict__ Kb,
    const unsigned short* __restrict__ Vb, const float* __restrict__ qin,
    const int* __restrict__ lens, float* __restrict__ out) {
  const int pi = blockIdx.x, h = blockIdx.y, b = blockIdx.z;
  const int lo = pi, hi = 31 - pi;
  const int bh = b * NHEAD + h;
  const int t = threadIdx.x, wave = t >> 6, lane = t & 63, quad = lane >> 4, l16 = lane & 15;
  const int sw = l16 & 7;
  const int klen = lens[b], qlen = lens[2 + b];

  __shared__ unsigned short Ks[2][64 * 64];
  __shared__ unsigned short VT[2][64 * 64];
  __shared__ unsigned short Ps[4][2][16 * 64];

  const unsigned short* Qp = Qb + (size_t)bh * SEQ * HDIM;
  const unsigned short* Kp = Kb + (size_t)bh * SEQ * HDIM;
  const unsigned short* Vp = Vb + (size_t)bh * SEQ * HDIM;

  const int qrLO = lo * 64 + wave * 16 + l16;
  const int qrHI = hi * 64 + wave * 16 + l16;
  const bf16x8 qlo0 = *(const bf16x8*)(Qp + (size_t)qrLO * HDIM + quad * 8);
  const bf16x8 qlo1 = *(const bf16x8*)(Qp + (size_t)qrLO * HDIM + 32 + quad * 8);
  const bf16x8 qhi0 = *(const bf16x8*)(Qp + (size_t)qrHI * HDIM + quad * 8);
  const bf16x8 qhi1 = *(const bf16x8*)(Qp + (size_t)qrHI * HDIM + 32 + quad * 8);

  const f32x4 fz = {0.f, 0.f, 0.f, 0.f};
  f32x4 oLO[4], oHI[4];
#pragma unroll
  for (int i = 0; i < 4; i++) { oLO[i] = fz; oHI[i] = fz; }
  float mLO = -__builtin_inff(), lLO = 0.f;
  float mHI = -__builtin_inff(), lHI = 0.f;

  const int klt = (klen + 63) >> 6;
  const int ktot = (hi + 1 < klt) ? hi + 1 : klt;

  // prologue: tile 0 into buffer 0
  stage_K(Kp, 0, Ks[0], t);
  bf16x8 va, vb2;
  load_V(Vp, 0, t, va, vb2);
  write_VT(VT[0], t, va, vb2);

  for (int kt = 0; kt < ktot; kt++) {
    const int cb = kt & 1, nb = cb ^ 1;
    const int key0 = kt * 64;
    __syncthreads();  // K[cb] arrived, VT[cb] written, buffers[nb] free
    if (kt + 1 < ktot) {
      stage_K(Kp, key0 + 64, Ks[nb], t);
      load_V(Vp, key0 + 64, t, va, vb2);
    }
    const bool loA = (kt <= lo);
    const unsigned short* ks = Ks[cb];
    const unsigned short* vt = VT[cb];

    f32x4 sLO[4], sHI[4];
#pragma unroll
    for (int nf = 0; nf < 4; nf++) {
      const bf16x8 kf0 = *(const bf16x8*)(ks + (nf * 16 + l16) * 64 + (quad ^ sw) * 8);
      const bf16x8 kf1 = *(const bf16x8*)(ks + (nf * 16 + l16) * 64 + ((quad + 4) ^ sw) * 8);
      f32x4 a = fz;
      a = __builtin_amdgcn_mfma_f32_16x16x32_bf16(kf0, qhi0, a, 0, 0, 0);
      a = __builtin_amdgcn_mfma_f32_16x16x32_bf16(kf1, qhi1, a, 0, 0, 0);
      sHI[nf] = a;
      if (loA) {
        f32x4 c = fz;
        c = __builtin_amdgcn_mfma_f32_16x16x32_bf16(kf0, qlo0, c, 0, 0, 0);
        c = __builtin_amdgcn_mfma_f32_16x16x32_bf16(kf1, qlo1, c, 0, 0, 0);
        sLO[nf] = c;
      }
    }

    softmax_update(sHI, key0, qrHI, klen, quad, l16, mHI, lHI, oHI, Ps[wave][1]);
    if (loA) softmax_update(sLO, key0, qrLO, klen, quad, l16, mLO, lLO, oLO, Ps[wave][0]);

    const bf16x8 pfh0 = *(const bf16x8*)(Ps[wave][1] + l16 * 64 + (quad ^ sw) * 8);
    const bf16x8 pfh1 = *(const bf16x8*)(Ps[wave][1] + l16 * 64 + ((quad + 4) ^ sw) * 8);
    bf16x8 pfl0, pfl1;
    if (loA) {
      pfl0 = *(const bf16x8*)(Ps[wave][0] + l16 * 64 + (quad ^ sw) * 8);
      pfl1 = *(const bf16x8*)(Ps[wave][0] + l16 * 64 + ((quad + 4) ^ sw) * 8);
    }
#pragma unroll
    for (int db = 0; db < 4; db++) {
      const bf16x8 vt0 = *(const bf16x8*)(vt + (db * 16 + l16) * 64 + (quad ^ sw) * 8);
      const bf16x8 vt1 = *(const bf16x8*)(vt + (db * 16 + l16) * 64 + ((quad + 4) ^ sw) * 8);
      oHI[db] = __builtin_amdgcn_mfma_f32_16x16x32_bf16(pfh0, vt0, oHI[db], 0, 0, 0);
      oHI[db] = __builtin_amdgcn_mfma_f32_16x16x32_bf16(pfh1, vt1, oHI[db], 0, 0, 0);
      if (loA) {
        oLO[db] = __builtin_amdgcn_mfma_f32_16x16x32_bf16(pfl0, vt0, oLO[db], 0, 0, 0);
        oLO[db] = __builtin_amdgcn_mfma_f32_16x16x32_bf16(pfl1, vt1, oLO[db], 0, 0, 0);
      }
    }
    if (kt + 1 < ktot) write_VT(VT[nb], t, va, vb2);  // next tile, other buffer
  }

  // epilogue: rows = quad*4+r, col = h*64 + db*16 + l16
  const float invLO = (lLO > 0.f) ? 1.f / lLO : 0.f;
  const float invHI = (lHI > 0.f) ? 1.f / lHI : 0.f;
  float ibLO[4], ibHI[4];
#pragma unroll
  for (int r = 0; r < 4; r++) {
    ibLO[r] = __shfl(invLO, quad * 4 + r, 64);
    ibHI[r] = __shfl(invHI, quad * 4 + r, 64);
  }
#pragma unroll
  for (int db = 0; db < 4; db++) {
    const int col = h * HDIM + db * 16 + l16;
#pragma unroll
    for (int r = 0; r < 4; r++) {
      const int iL = lo * 64 + wave * 16 + quad * 4 + r;
      const int iH = hi * 64 + wave * 16 + quad * 4 + r;
      const size_t oL = (size_t)(b * SEQ + iL) * DMODEL + col;
      const size_t oH = (size_t)(b * SEQ + iH) * DMODEL + col;
      out[oL] = ((iL < qlen) ? oLO[db][r] * ibLO[r] : 0.f) + qin[oL];
      out[oH] = ((iH < qlen) ? oHI[db][r] * ibHI[r] : 0.f) + qin[oH];
    }
  }
}

extern "C" void kernel_launch(void* const* d_in, const int* in_sizes, int n_in,
                              void* d_out, int out_size, void* d_ws, size_t ws_size,
                              hipStream_t stream) {
  (void)in_sizes; (void)n_in; (void)out_size; (void)ws_size;
  const float* q = (const float*)d_in[0];
  const float* k = (const float*)d_in[1];
  const float* v = (const float*)d_in[2];
  const float* Wq = (const float*)d_in[3];
  const float* bq = (const float*)d_in[4];
  const float* Wk = (const float*)d_in[5];
  const float* bk = (const float*)d_in[6];
  const float* Wv = (const float*)d_in[7];
  const float* bv = (const float*)d_in[8];
  const unsigned char* kpm = (const unsigned char*)d_in[9];
  const unsigned char* qpm = (const unsigned char*)d_in[10];
  float* out = (float*)d_out;

  const size_t tsz = (size_t)BATCH * SEQ * DMODEL;  // 4 Mi
  const size_t wsz = (size_t)DMODEL * DMODEL;       // 1 Mi

  char* ws = (char*)d_ws;
  int* lens = (int*)ws;
  unsigned short* cvt_base = (unsigned short*)(ws + 256);
  unsigned short* qb16 = cvt_base;
  unsigned short* kb16 = qb16 + tsz;
  unsigned short* vb16 = kb16 + tsz;
  unsigned short* Wqb = vb16 + tsz;
  unsigned short* Wkb = Wqb + wsz;
  unsigned short* Wvb = Wkb + wsz;
  unsigned short* Qw = Wvb + wsz;
  unsigned short* Kw = Qw + tsz;
  unsigned short* Vw = Kw + tsz;

  lens_kernel<<<dim3(1), dim3(256), 0, stream>>>(kpm, qpm, lens);
  cvt_all<<<dim3(15360), dim3(256), 0, stream>>>(q, k, v, Wq, Wk, Wv, cvt_base);
  qkv_proj<<<dim3(8, 32, 3), dim3(256), 0, stream>>>(qb16, kb16, vb16, Wqb, bq, Wkb, bk, Wvb, bv, Qw, Kw, Vw);
  attn_kernel<<<dim3(16, NHEAD, BATCH), dim3(256), 0, stream>>>(Qw, Kw, Vw, q, lens, out);
}